// Round 10
// baseline (70.670 us; speedup 1.0000x reference)
//
#include <hip/hip_runtime.h>

#define S 512
#define Dm 512

typedef __bf16 bf16x8 __attribute__((ext_vector_type(8)));
typedef float f32x4 __attribute__((ext_vector_type(4)));

// ---------------- bf16 MFMA GEMM with inline fp32->bf16 conversion ----------------
// O = A*W + bias. W fp32 [K][N] read strided (lane-coalesced) + cvt.
// 32x32 tile, 256 thr = 2x2 waves of one 16x16 MFMA each.
template<bool A_BF16>
__global__ __launch_bounds__(256) void gemm_icvt(
    const void* __restrict__ Aptr,
    const float* __restrict__ W0, const float* __restrict__ W1, const float* __restrict__ W2,
    const float* __restrict__ b0, const float* __restrict__ b1, const float* __restrict__ b2,
    float* __restrict__ O0, float* __restrict__ O1, float* __restrict__ O2)
{
    int blk = blockIdx.x;
    int m = blk >> 8;
    int tile = blk & 255;
    const float* W = (m == 0) ? W0 : (m == 1) ? W1 : W2;
    const float* bias = (m == 0) ? b0 : (m == 1) ? b1 : b2;
    float* O = (m == 0) ? O0 : (m == 1) ? O1 : O2;
    int rt = tile >> 4, ct = tile & 15;

    int u = threadIdx.x;
    int w = u >> 6, lane = u & 63;
    int r = lane & 15, kg = lane >> 4;

    int row0 = (rt << 5) + ((w >> 1) << 4);
    int col0 = (ct << 5) + ((w & 1) << 4);

    const float* Bp = W + (kg << 3) * Dm + col0 + r;

    f32x4 acc = {0.f, 0.f, 0.f, 0.f};

    #pragma unroll 4
    for (int k0 = 0; k0 < Dm; k0 += 32) {
        bf16x8 a;
        if constexpr (A_BF16) {
            const __bf16* Ab = (const __bf16*)Aptr;
            a = *(const bf16x8*)(Ab + (row0 + r) * Dm + k0 + (kg << 3));
        } else {
            const float* Af = (const float*)Aptr;
            float4 a0 = *(const float4*)(Af + (row0 + r) * Dm + k0 + (kg << 3));
            float4 a1 = *(const float4*)(Af + (row0 + r) * Dm + k0 + (kg << 3) + 4);
            a[0] = (__bf16)a0.x; a[1] = (__bf16)a0.y; a[2] = (__bf16)a0.z; a[3] = (__bf16)a0.w;
            a[4] = (__bf16)a1.x; a[5] = (__bf16)a1.y; a[6] = (__bf16)a1.z; a[7] = (__bf16)a1.w;
        }
        bf16x8 b;
        #pragma unroll
        for (int t = 0; t < 8; ++t)
            b[t] = (__bf16)Bp[(k0 + t) * Dm];
        acc = __builtin_amdgcn_mfma_f32_16x16x32_bf16(a, b, acc, 0, 0, 0);
    }

    int orow = row0 + (kg << 2);
    float bb = bias[col0 + r];
    #pragma unroll
    for (int t = 0; t < 4; ++t)
        O[(orow + t) * Dm + col0 + r] = acc[t] + bb;
}

// ---------------- fused z' + ctx: one block owns 16 i-rows x all 512 j ----------------
// grid 256 = 8 heads * 32 i-tiles(16 rows). 512 thr = 8 waves, 1 block/CU.
// Phase A: lane = (il = lane&15 -> i, s = lane>>4), wave w: j-group g=w*4+s (16 j's).
//          Q-row in 64 VGPRs; K per-lane float4; z' -> zs LDS + zsum per lane.
//          zs -> zp (global, same-XCD L2) coalesced.
// Phase B: round-8 ctx structure for 16 rows: vv per-lane V, uniform z float4 loads,
//          cross-wave reduce in LDS (aliases zs), ctx -> bf16.
__global__ __launch_bounds__(512) void zctx_kernel(
    const float* __restrict__ Q, const float* __restrict__ K, const float* __restrict__ V,
    const float* __restrict__ mask, const float* __restrict__ gamma,
    const float* __restrict__ alpha,
    float* __restrict__ zp, __bf16* __restrict__ ctxb)
{
    int blk = blockIdx.x;
    int h  = blk >> 5;
    int it = blk & 31;
    int i0 = it << 4;
    int c0 = h << 6;

    int u = threadIdx.x;
    int w = u >> 6, lane = u & 63;
    int il = lane & 15, s = lane >> 4;

    __shared__ float zs[16][516];      // 33 KB; pitch 516 -> rows 16B-aligned
    __shared__ float partial[8][16];   // Zsum partials per wave

    // ---- phase A: z' ----
    float qreg[64];
    #pragma unroll
    for (int t = 0; t < 16; ++t) {
        float4 qv = *(const float4*)(Q + (i0 + il) * Dm + c0 + (t << 2));
        qreg[4 * t + 0] = qv.x; qreg[4 * t + 1] = qv.y;
        qreg[4 * t + 2] = qv.z; qreg[4 * t + 3] = qv.w;
    }

    float sc = 1.0f / (gamma[0] * 8.0f);
    float al = alpha[0];

    int jg0 = ((w << 2) + s) << 4;     // per-lane j-group base (0..496)
    float zsum = 0.f;
    #pragma unroll 2
    for (int jj = 0; jj < 16; ++jj) {
        int j = jg0 + jj;
        const float* kr = K + j * Dm + c0;        // per-lane (4 distinct / wave)
        float a0 = 0.f, a1 = 0.f, a2 = 0.f, a3 = 0.f;
        #pragma unroll
        for (int t = 0; t < 16; ++t) {
            float4 kb = *(const float4*)(kr + (t << 2));
            a0 += fabsf(qreg[4 * t + 0] - kb.x);
            a1 += fabsf(qreg[4 * t + 1] - kb.y);
            a2 += fabsf(qreg[4 * t + 2] - kb.z);
            a3 += fabsf(qreg[4 * t + 3] - kb.w);
        }
        float madd = (1.0f - mask[j]) * 1e6f;
        float zpv = fmaxf((a0 + a1 + a2 + a3) * sc - al, 0.0f) + madd;
        zs[il][j] = zpv;
        zsum += zpv;
    }
    {   // reduce zsum across the 4 subgroups sharing this i (lanes ^16, ^32)
        float r = zsum;
        r += __shfl_xor(r, 16, 64);
        r += __shfl_xor(r, 32, 64);
        if (s == 0) partial[w][il] = r;
    }
    __syncthreads();

    // ---- zs -> zp (coalesced), rows i0..i0+15 ----
    {
        int row = u >> 5;              // 0..15
        int cb = (u & 31) << 2;        // 0..124
        float* orow = zp + ((h << 9) + i0 + row) * S;
        #pragma unroll
        for (int q = 0; q < 4; ++q) {
            int col = cb + (q << 7);
            float4 o = *(const float4*)&zs[row][col];
            *(float4*)(orow + col) = o;
        }
    }
    __syncthreads();                   // stores drained; zs free for reuse

    // ---- phase B: ctx ----
    float (*part)[16][64] = (float (*)[16][64])&zs[0][0];   // 32 KB alias
    int wu = __builtin_amdgcn_readfirstlane(w);
    float acc[16][4] = {};

    #pragma unroll
    for (int cch = 0; cch < 4; ++cch) {
        int jg = (cch << 7) + (wu << 4);                    // uniform
        float vv[16];
        #pragma unroll
        for (int t = 0; t < 16; ++t)
            vv[t] = V[(jg + t) * Dm + c0 + lane];           // coalesced b32

        const float* zbase = zp + ((h << 9) + i0) * S + jg; // uniform, L2-hot
        #pragma unroll
        for (int ii = 0; ii < 16; ++ii) {
            const float* zrow = zbase + ii * S;
            #pragma unroll
            for (int q4 = 0; q4 < 4; ++q4) {
                float4 z4 = *(const float4*)(zrow + (q4 << 2));
                acc[ii][0] += fmaxf(vv[(q4 << 2) + 0], z4.x);
                acc[ii][1] += fmaxf(vv[(q4 << 2) + 1], z4.y);
                acc[ii][2] += fmaxf(vv[(q4 << 2) + 2], z4.z);
                acc[ii][3] += fmaxf(vv[(q4 << 2) + 3], z4.w);
            }
        }
    }

    #pragma unroll
    for (int ii = 0; ii < 16; ++ii)
        part[w][ii][lane] = (acc[ii][0] + acc[ii][1]) + (acc[ii][2] + acc[ii][3]);
    __syncthreads();

    #pragma unroll
    for (int rep = 0; rep < 2; ++rep) {
        int ii = (u >> 6) + (rep << 3);      // 0..7 then 8..15
        float ssum = 0.f;
        #pragma unroll
        for (int ww = 0; ww < 8; ++ww) ssum += part[ww][ii][lane];
        float zt = 0.f;
        #pragma unroll
        for (int p = 0; p < 8; ++p) zt += partial[p][ii];
        ctxb[(i0 + ii) * Dm + c0 + lane] = (__bf16)(ssum - zt);
    }
}

extern "C" void kernel_launch(void* const* d_in, const int* in_sizes, int n_in,
                              void* d_out, int out_size, void* d_ws, size_t ws_size,
                              hipStream_t stream) {
    const float* hs    = (const float*)d_in[0];
    const float* mask  = (const float*)d_in[1];
    const float* Wq    = (const float*)d_in[2];
    const float* bq    = (const float*)d_in[3];
    const float* Wk    = (const float*)d_in[4];
    const float* bk    = (const float*)d_in[5];
    const float* Wv    = (const float*)d_in[6];
    const float* bv    = (const float*)d_in[7];
    const float* Wo    = (const float*)d_in[8];
    const float* bo    = (const float*)d_in[9];
    const float* gamma = (const float*)d_in[10];
    const float* alpha = (const float*)d_in[11];
    float* out = (float*)d_out;

    char* base = (char*)d_ws;
    float*  zp  = (float*)(base);                      // 8 MB
    float*  Qb  = (float*)(base + (8u << 20));         // 1 MB
    float*  Kb  = Qb + S * Dm;                         // 1 MB
    float*  Vb  = Kb + S * Dm;                         // 1 MB
    __bf16* Cbf = (__bf16*)(Vb + S * Dm);              // 0.5 MB

    hipLaunchKernelGGL((gemm_icvt<false>), dim3(768), dim3(256), 0, stream,
                       (const void*)hs, Wq, Wk, Wv, bq, bk, bv, Qb, Kb, Vb);
    hipLaunchKernelGGL(zctx_kernel, dim3(256), dim3(512), 0, stream,
                       Qb, Kb, Vb, mask, gamma, alpha, zp, Cbf);
    hipLaunchKernelGGL((gemm_icvt<true>), dim3(256), dim3(256), 0, stream,
                       (const void*)Cbf, Wo, Wo, Wo, bo, bo, bo, out, out, out);
}